// Round 1
// baseline (401.362 us; speedup 1.0000x reference)
//
#include <hip/hip_runtime.h>

constexpr int NROWS  = 131072;
constexpr int LDIM   = 300;
constexpr int KDIM   = 600;
constexpr int NPAD   = 320;
constexpr int KGRP   = 76;               // 608 / 8
constexpr int MTILE  = 64;
constexpr int NBLKS  = NROWS / MTILE;    // 2048
constexpr int KSTEPS = 19;               // 608 / 32
constexpr int WT_ELEMS = KGRP * NPAD * 8;        // 194560 bf16
constexpr size_t PART_OFF = 393216;              // byte offset of partials in ws

typedef __bf16 bf16x8 __attribute__((ext_vector_type(8)));
typedef float  f32x4  __attribute__((ext_vector_type(4)));

__device__ __forceinline__ unsigned short f2bf(float f) {
    unsigned u = __float_as_uint(f);
    u += 0x7fffu + ((u >> 16) & 1u);      // RNE; inputs are finite
    return (unsigned short)(u >> 16);
}

// ---------------- kernel 1: W1 -> bf16, fragment-ready layout [kg][n][j] ----
__global__ void prep_w1(const float* __restrict__ w1, unsigned short* __restrict__ wt) {
    int idx = blockIdx.x * 256 + threadIdx.x;
    if (idx >= WT_ELEMS) return;
    int j    = idx & 7;
    int rest = idx >> 3;
    int n    = rest % NPAD;
    int kg   = rest / NPAD;
    int k    = kg * 8 + j;
    float v = 0.f;
    if (k < KDIM && n < LDIM) v = w1[k * LDIM + n];
    wt[idx] = f2bf(v);
}

// ---------------- kernel 2: fused GEMM + epilogue ---------------------------
// Whole-tile LDS staging: one barrier per block; compute loop is barrier-free.
// A_lds layout is fragment-ready [kg][row][8] so every ds_read_b128 is
// lane-contiguous (conflict-free) and every MFMA fragment is one read.
__launch_bounds__(256, 2)
__global__ void main_kernel(const float* __restrict__ sbj, const float* __restrict__ obj,
                            const float* __restrict__ rlts,
                            const float* __restrict__ spa_w, const float* __restrict__ spa_b,
                            const float* __restrict__ b1, const float* __restrict__ w2,
                            const float* __restrict__ b2,
                            const unsigned short* __restrict__ wt,
                            float* __restrict__ out_scores, float* __restrict__ part) {
    // 76 kgroups * 64 rows * 8 bf16 = 77824 B
    __shared__ __attribute__((aligned(16))) unsigned short A_lds[KGRP * MTILE * 8];
    __shared__ float lanpart[4][MTILE];
    __shared__ float redbuf[4][8];

    const int tid  = threadIdx.x;
    const int lane = tid & 63;
    const int wv   = tid >> 6;     // 0..3 — each wave owns 80 cols
    const int l4   = lane & 15;    // MFMA row/col index
    const int q4   = lane >> 4;    // MFMA k-group (0..3)
    const int nbase = wv * 80;

    const int  blk  = blockIdx.x;
    const long row0 = (long)blk * MTILE;

    // A staging map: thread t handles rows (t>>3) and (t>>3)+32, k-quad t&7
    const int a_quad = tid & 7;
    const int a_row  = tid >> 3;   // 0..31

    // ---- stage the WHOLE 64x608 tile: fp32 -> relu -> bf16, fragment-ready ----
    // 38 independent float4 loads per thread, straight-line: max memory parallelism.
    #pragma unroll
    for (int kc = 0; kc < KSTEPS; ++kc) {
        const int k0 = kc * 32 + a_quad * 4;   // multiple of 4; 300 % 4 == 0, no straddle
        const int kg = k0 >> 3;
        const int j0 = k0 & 7;                 // 0 or 4
        #pragma unroll
        for (int i = 0; i < 2; ++i) {
            const int  row  = a_row + i * 32;
            const long grow = row0 + row;
            float4 v = make_float4(0.f, 0.f, 0.f, 0.f);
            if (k0 < LDIM)       v = *(const float4*)(sbj + grow * LDIM + k0);
            else if (k0 < KDIM)  v = *(const float4*)(obj + grow * LDIM + (k0 - LDIM));
            unsigned h0 = f2bf(fmaxf(v.x, 0.f));
            unsigned h1 = f2bf(fmaxf(v.y, 0.f));
            unsigned h2 = f2bf(fmaxf(v.z, 0.f));
            unsigned h3 = f2bf(fmaxf(v.w, 0.f));
            uint2 pk = make_uint2(h0 | (h1 << 16), h2 | (h3 << 16));
            *(uint2*)&A_lds[(kg * MTILE + row) * 8 + j0] = pk;
        }
    }

    f32x4 acc[4][5];
    #pragma unroll
    for (int rt = 0; rt < 4; ++rt)
        #pragma unroll
        for (int ct = 0; ct < 5; ++ct)
            acc[rt][ct] = (f32x4)(0.f);

    __syncthreads();               // the only barrier before the epilogue

    // Hoisted bases: A_lds short-index = kt*2048 + rt*128 + (q4*512 + l4*8)
    const int abase = q4 * 512 + l4 * 8;
    const unsigned short* wbase = wt + ((size_t)q4 * NPAD + nbase + l4) * 8;

    // ---- barrier-free K loop: 19 x (4 ds_read_b128 + 5 L2 loads + 20 MFMA) ----
    #pragma unroll
    for (int kt = 0; kt < KSTEPS; ++kt) {
        bf16x8 af[4];
        #pragma unroll
        for (int rt = 0; rt < 4; ++rt)
            af[rt] = *(const bf16x8*)&A_lds[kt * 2048 + rt * 128 + abase];

        bf16x8 bfr[5];
        #pragma unroll
        for (int ct = 0; ct < 5; ++ct)
            bfr[ct] = *(const bf16x8*)(wbase + (size_t)kt * 4 * NPAD * 8 + ct * 16 * 8);

        #pragma unroll
        for (int ct = 0; ct < 5; ++ct)
            #pragma unroll
            for (int rt = 0; rt < 4; ++rt)
                acc[rt][ct] = __builtin_amdgcn_mfma_f32_16x16x32_bf16(af[rt], bfr[ct], acc[rt][ct], 0, 0, 0);
    }

    // ---- epilogue: bias + relu + dot with w2 ----
    // C/D layout (m89): col = lane&15, row = (lane>>4)*4 + reg
    float part_r[4][4];
    #pragma unroll
    for (int rt = 0; rt < 4; ++rt)
        #pragma unroll
        for (int r = 0; r < 4; ++r) part_r[rt][r] = 0.f;

    #pragma unroll
    for (int ct = 0; ct < 5; ++ct) {
        const int n = nbase + ct * 16 + l4;
        if (n < LDIM) {
            const float b1n = b1[n];
            const float w2n = w2[n];
            #pragma unroll
            for (int rt = 0; rt < 4; ++rt)
                #pragma unroll
                for (int r = 0; r < 4; ++r) {
                    float h = fmaxf(acc[rt][ct][r] + b1n, 0.f);
                    part_r[rt][r] = fmaf(h, w2n, part_r[rt][r]);
                }
        }
    }
    // reduce over the 16 col-lanes (xor of lane bits 0..3)
    #pragma unroll
    for (int off = 1; off < 16; off <<= 1)
        #pragma unroll
        for (int rt = 0; rt < 4; ++rt)
            #pragma unroll
            for (int r = 0; r < 4; ++r)
                part_r[rt][r] += __shfl_xor(part_r[rt][r], off, 64);

    if (l4 == 0) {
        #pragma unroll
        for (int rt = 0; rt < 4; ++rt)
            #pragma unroll
            for (int r = 0; r < 4; ++r)
                lanpart[wv][rt * 16 + q4 * 4 + r] = part_r[rt][r];
    }
    __syncthreads();

    // ---- per-row: box features, sigmoid, loss terms ----
    float s_loss = 0.f, s_cp = 0.f, s_cn = 0.f, s_pr = 0.f, s_nr = 0.f;
    if (tid < MTILE) {
        const long g   = row0 + tid;
        const float lan = lanpart[0][tid] + lanpart[1][tid] + lanpart[2][tid] + lanpart[3][tid] + b2[0];
        const float* rr = rlts + g * 15;
        const float label = rr[4];
        const float sx1 = rr[5],  sy1 = rr[6],  sx2 = rr[7],  sy2 = rr[8];
        const float ox1 = rr[10], oy1 = rr[11], ox2 = rr[12], oy2 = rr[13];
        const float sw = sx2 - sx1, sh = sy2 - sy1, ow = ox2 - ox1, oh = oy2 - oy1;
        float bs = spa_w[0] * ((sx1 - ox1) / sw)
                 + spa_w[1] * ((sy1 - oy1) / sh)
                 + spa_w[2] * logf(sw / ow)
                 + spa_w[3] * logf(sh / oh)
                 + spa_w[4] * ((ox1 - sx1) / ow)
                 + spa_w[5] * ((oy1 - sy1) / oh)
                 + spa_w[6] * logf(ow / sw)
                 + spa_w[7] * logf(oh / sh)
                 + spa_b[0];
        const float z = lan + bs;
        const float s = 1.f / (1.f + expf(-z));
        out_scores[g] = s;
        const float ls = fmaxf(logf(fminf(fmaxf(s, 1e-12f), 1.f)), -100.f);
        const float l1 = fmaxf(logf(fminf(fmaxf(1.f - s, 1e-12f), 1.f)), -100.f);
        const bool ys = label > 0.f;
        s_loss = ys ? ls : l1;
        s_cp   = ys ? 1.f : 0.f;
        s_cn   = ys ? 0.f : 1.f;
        s_pr   = (!ys && s >= 0.5f) ? 1.f : 0.f;  // "N_pos_right" per reference
        s_nr   = (ys && s < 0.5f)  ? 1.f : 0.f;   // "N_neg_right" per reference
    }
    #pragma unroll
    for (int off = 1; off < 64; off <<= 1) {
        s_loss += __shfl_xor(s_loss, off, 64);
        s_cp   += __shfl_xor(s_cp, off, 64);
        s_cn   += __shfl_xor(s_cn, off, 64);
        s_pr   += __shfl_xor(s_pr, off, 64);
        s_nr   += __shfl_xor(s_nr, off, 64);
    }
    if (lane == 0) {
        redbuf[wv][0] = s_loss; redbuf[wv][1] = s_cp; redbuf[wv][2] = s_cn;
        redbuf[wv][3] = s_pr;   redbuf[wv][4] = s_nr;
    }
    __syncthreads();
    if (tid == 0) {
        float t0 = 0.f, t1 = 0.f, t2 = 0.f, t3 = 0.f, t4 = 0.f;
        for (int w = 0; w < 4; ++w) {
            t0 += redbuf[w][0]; t1 += redbuf[w][1]; t2 += redbuf[w][2];
            t3 += redbuf[w][3]; t4 += redbuf[w][4];
        }
        part[blk * 8 + 0] = t0; part[blk * 8 + 1] = t1; part[blk * 8 + 2] = t2;
        part[blk * 8 + 3] = t3; part[blk * 8 + 4] = t4;
    }
}

// ---------------- kernel 3: fold 2048 block partials ------------------------
__global__ void final_reduce(const float* __restrict__ part, float* __restrict__ out) {
    __shared__ float red[4][8];
    const int tid = threadIdx.x;
    const int lane = tid & 63, wv = tid >> 6;
    float a0 = 0.f, a1 = 0.f, a2 = 0.f, a3 = 0.f, a4 = 0.f;
    for (int b = tid; b < NBLKS; b += 256) {
        a0 += part[b * 8 + 0]; a1 += part[b * 8 + 1]; a2 += part[b * 8 + 2];
        a3 += part[b * 8 + 3]; a4 += part[b * 8 + 4];
    }
    #pragma unroll
    for (int off = 1; off < 64; off <<= 1) {
        a0 += __shfl_xor(a0, off, 64); a1 += __shfl_xor(a1, off, 64);
        a2 += __shfl_xor(a2, off, 64); a3 += __shfl_xor(a3, off, 64);
        a4 += __shfl_xor(a4, off, 64);
    }
    if (lane == 0) { red[wv][0] = a0; red[wv][1] = a1; red[wv][2] = a2; red[wv][3] = a3; red[wv][4] = a4; }
    __syncthreads();
    if (tid == 0) {
        float t0 = 0.f, t1 = 0.f, t2 = 0.f, t3 = 0.f, t4 = 0.f;
        for (int w = 0; w < 4; ++w) {
            t0 += red[w][0]; t1 += red[w][1]; t2 += red[w][2]; t3 += red[w][3]; t4 += red[w][4];
        }
        out[NROWS + 0] = -t0 / (float)NROWS;       // loss
        out[NROWS + 1] = t3 / t1;                  // recall_pos
        out[NROWS + 2] = t4 / t2;                  // recall_neg
        out[NROWS + 3] = (t3 + t4) / (t1 + t2);    // recall_all
    }
}

extern "C" void kernel_launch(void* const* d_in, const int* in_sizes, int n_in,
                              void* d_out, int out_size, void* d_ws, size_t ws_size,
                              hipStream_t stream) {
    const float* sbj   = (const float*)d_in[0];
    const float* obj   = (const float*)d_in[1];
    const float* rlts  = (const float*)d_in[2];
    const float* spa_w = (const float*)d_in[3];
    const float* spa_b = (const float*)d_in[4];
    const float* w1    = (const float*)d_in[5];
    const float* b1    = (const float*)d_in[6];
    const float* w2    = (const float*)d_in[7];
    const float* b2    = (const float*)d_in[8];
    float* out = (float*)d_out;

    unsigned short* wt = (unsigned short*)d_ws;
    float* part = (float*)((char*)d_ws + PART_OFF);

    prep_w1<<<(WT_ELEMS + 255) / 256, 256, 0, stream>>>(w1, wt);
    main_kernel<<<NBLKS, 256, 0, stream>>>(sbj, obj, rlts, spa_w, spa_b, b1, w2, b2, wt, out, part);
    final_reduce<<<1, 256, 0, stream>>>(part, out);
}

// Round 2
// 380.459 us; speedup vs baseline: 1.0549x; 1.0549x over previous
//
#include <hip/hip_runtime.h>

constexpr int NROWS  = 131072;
constexpr int LDIM   = 300;
constexpr int KDIM   = 600;
constexpr int NPAD   = 320;
constexpr int KGRP   = 76;               // 608 / 8
constexpr int MTILE  = 64;
constexpr int NBLKS  = NROWS / MTILE;    // 2048
constexpr int KSTEPS = 19;               // 608 / 32
constexpr int WT_ELEMS = KGRP * NPAD * 8;        // 194560 bf16
constexpr size_t PART_OFF = 393216;              // byte offset of partials in ws
constexpr int ASTRIDE = 40;              // shorts per row (80 B) — conflict-free

typedef __bf16 bf16x8 __attribute__((ext_vector_type(8)));
typedef float  f32x4  __attribute__((ext_vector_type(4)));

__device__ __forceinline__ unsigned short f2bf(float f) {
    unsigned u = __float_as_uint(f);
    u += 0x7fffu + ((u >> 16) & 1u);      // RNE; inputs are finite
    return (unsigned short)(u >> 16);
}

// ---------------- kernel 1: W1 -> bf16, fragment-ready layout [kg][n][j] ----
__global__ void prep_w1(const float* __restrict__ w1, unsigned short* __restrict__ wt) {
    int idx = blockIdx.x * 256 + threadIdx.x;
    if (idx >= WT_ELEMS) return;
    int j    = idx & 7;
    int rest = idx >> 3;
    int n    = rest % NPAD;
    int kg   = rest / NPAD;
    int k    = kg * 8 + j;
    float v = 0.f;
    if (k < KDIM && n < LDIM) v = w1[k * LDIM + n];
    wt[idx] = f2bf(v);
}

// ---------------- kernel 2: fused GEMM + epilogue ---------------------------
// Depth-2 register prefetch: load_A(kt+3) issued at END of iter kt, consumed
// by store_A two full iterations later — HBM latency (~900 cy) fits the
// ~2-iteration budget, so the per-iter vmcnt stall of the depth-1 version
// disappears and loads stay in flight across barriers (T4 principle).
__launch_bounds__(256, 3)
__global__ void main_kernel(const float* __restrict__ sbj, const float* __restrict__ obj,
                            const float* __restrict__ rlts,
                            const float* __restrict__ spa_w, const float* __restrict__ spa_b,
                            const float* __restrict__ b1, const float* __restrict__ w2,
                            const float* __restrict__ b2,
                            const unsigned short* __restrict__ wt,
                            float* __restrict__ out_scores, float* __restrict__ part) {
    __shared__ __attribute__((aligned(16))) short A_lds[2][MTILE * ASTRIDE]; // 10240 B
    __shared__ float lanpart[4][MTILE];
    __shared__ float redbuf[4][8];

    const int tid  = threadIdx.x;
    const int lane = tid & 63;
    const int wv   = tid >> 6;     // 0..3 — each wave owns 80 cols
    const int l4   = lane & 15;    // MFMA row/col index
    const int q4   = lane >> 4;    // MFMA k-group (0..3)
    const int nbase = wv * 80;

    const int  blk  = blockIdx.x;
    const long row0 = (long)blk * MTILE;

    // A staging map: thread t loads rows (t>>3) and (t>>3)+32, k-quad t&7
    const int a_quad = tid & 7;
    const int a_row  = tid >> 3;   // 0..31

    f32x4 acc[4][5];
    #pragma unroll
    for (int rt = 0; rt < 4; ++rt)
        #pragma unroll
        for (int ct = 0; ct < 5; ++ct)
            acc[rt][ct] = (f32x4)(0.f);

    float4 pre[3][2];              // 3 rotating slots, static-indexed (full unroll)

    auto load_A = [&](int kt, int slot) {
        const int k0 = kt * 32 + a_quad * 4;   // mult of 4; 300 % 4 == 0 → no straddle
        #pragma unroll
        for (int i = 0; i < 2; ++i) {
            const long grow = row0 + a_row + i * 32;
            if (k0 < LDIM)       pre[slot][i] = *(const float4*)(sbj + grow * LDIM + k0);
            else if (k0 < KDIM)  pre[slot][i] = *(const float4*)(obj + grow * LDIM + (k0 - LDIM));
            else                 pre[slot][i] = make_float4(0.f, 0.f, 0.f, 0.f);
        }
    };
    auto store_A = [&](int slot, int buf) {
        #pragma unroll
        for (int i = 0; i < 2; ++i) {
            const int row = a_row + i * 32;
            unsigned h0 = f2bf(fmaxf(pre[slot][i].x, 0.f));
            unsigned h1 = f2bf(fmaxf(pre[slot][i].y, 0.f));
            unsigned h2 = f2bf(fmaxf(pre[slot][i].z, 0.f));
            unsigned h3 = f2bf(fmaxf(pre[slot][i].w, 0.f));
            uint2 pk = make_uint2(h0 | (h1 << 16), h2 | (h3 << 16));
            *(uint2*)&A_lds[buf][row * ASTRIDE + a_quad * 4] = pk;
        }
    };

    // Prologue: fill the pipeline 3 deep, commit step 0 to LDS.
    load_A(0, 0);
    load_A(1, 1);
    load_A(2, 2);
    store_A(0, 0);                 // waits only on load 0; loads 1,2 stay in flight

    #pragma unroll
    for (int kt = 0; kt < KSTEPS; ++kt) {
        const int buf = kt & 1;
        __syncthreads();           // A_lds[buf] ready; all reads of buf^1 retired

        // B fragments straight from global (L2-resident, coalesced 16B/lane)
        bf16x8 bfr[5];
        #pragma unroll
        for (int ct = 0; ct < 5; ++ct) {
            const int kg = kt * 4 + q4;
            bfr[ct] = *(const bf16x8*)(wt + ((size_t)kg * NPAD + nbase + ct * 16 + l4) * 8);
        }

        // A fragments from LDS (conflict-free stride-40 layout)
        bf16x8 af[4];
        #pragma unroll
        for (int rt = 0; rt < 4; ++rt)
            af[rt] = *(const bf16x8*)&A_lds[buf][(rt * 16 + l4) * ASTRIDE + q4 * 8];

        #pragma unroll
        for (int ct = 0; ct < 5; ++ct)
            #pragma unroll
            for (int rt = 0; rt < 4; ++rt)
                acc[rt][ct] = __builtin_amdgcn_mfma_f32_16x16x32_bf16(af[rt], bfr[ct], acc[rt][ct], 0, 0, 0);

        // Commit step kt+1 (loaded two iterations ago — latency fully hidden),
        // then top up the pipeline with step kt+3.
        if (kt + 1 < KSTEPS) store_A((kt + 1) % 3, buf ^ 1);
        if (kt + 3 < KSTEPS) load_A(kt + 3, kt % 3);
    }

    // ---- epilogue: bias + relu + dot with w2 ----
    // C/D layout (m89): col = lane&15, row = (lane>>4)*4 + reg
    float part_r[4][4];
    #pragma unroll
    for (int rt = 0; rt < 4; ++rt)
        #pragma unroll
        for (int r = 0; r < 4; ++r) part_r[rt][r] = 0.f;

    #pragma unroll
    for (int ct = 0; ct < 5; ++ct) {
        const int n = nbase + ct * 16 + l4;
        if (n < LDIM) {
            const float b1n = b1[n];
            const float w2n = w2[n];
            #pragma unroll
            for (int rt = 0; rt < 4; ++rt)
                #pragma unroll
                for (int r = 0; r < 4; ++r) {
                    float h = fmaxf(acc[rt][ct][r] + b1n, 0.f);
                    part_r[rt][r] = fmaf(h, w2n, part_r[rt][r]);
                }
        }
    }
    // reduce over the 16 col-lanes (xor of lane bits 0..3)
    #pragma unroll
    for (int off = 1; off < 16; off <<= 1)
        #pragma unroll
        for (int rt = 0; rt < 4; ++rt)
            #pragma unroll
            for (int r = 0; r < 4; ++r)
                part_r[rt][r] += __shfl_xor(part_r[rt][r], off, 64);

    if (l4 == 0) {
        #pragma unroll
        for (int rt = 0; rt < 4; ++rt)
            #pragma unroll
            for (int r = 0; r < 4; ++r)
                lanpart[wv][rt * 16 + q4 * 4 + r] = part_r[rt][r];
    }
    __syncthreads();

    // ---- per-row: box features, sigmoid, loss terms ----
    float s_loss = 0.f, s_cp = 0.f, s_cn = 0.f, s_pr = 0.f, s_nr = 0.f;
    if (tid < MTILE) {
        const long g   = row0 + tid;
        const float lan = lanpart[0][tid] + lanpart[1][tid] + lanpart[2][tid] + lanpart[3][tid] + b2[0];
        const float* rr = rlts + g * 15;
        const float label = rr[4];
        const float sx1 = rr[5],  sy1 = rr[6],  sx2 = rr[7],  sy2 = rr[8];
        const float ox1 = rr[10], oy1 = rr[11], ox2 = rr[12], oy2 = rr[13];
        const float sw = sx2 - sx1, sh = sy2 - sy1, ow = ox2 - ox1, oh = oy2 - oy1;
        float bs = spa_w[0] * ((sx1 - ox1) / sw)
                 + spa_w[1] * ((sy1 - oy1) / sh)
                 + spa_w[2] * logf(sw / ow)
                 + spa_w[3] * logf(sh / oh)
                 + spa_w[4] * ((ox1 - sx1) / ow)
                 + spa_w[5] * ((oy1 - sy1) / oh)
                 + spa_w[6] * logf(ow / sw)
                 + spa_w[7] * logf(oh / sh)
                 + spa_b[0];
        const float z = lan + bs;
        const float s = 1.f / (1.f + expf(-z));
        out_scores[g] = s;
        const float ls = fmaxf(logf(fminf(fmaxf(s, 1e-12f), 1.f)), -100.f);
        const float l1 = fmaxf(logf(fminf(fmaxf(1.f - s, 1e-12f), 1.f)), -100.f);
        const bool ys = label > 0.f;
        s_loss = ys ? ls : l1;
        s_cp   = ys ? 1.f : 0.f;
        s_cn   = ys ? 0.f : 1.f;
        s_pr   = (!ys && s >= 0.5f) ? 1.f : 0.f;  // "N_pos_right" per reference
        s_nr   = (ys && s < 0.5f)  ? 1.f : 0.f;   // "N_neg_right" per reference
    }
    #pragma unroll
    for (int off = 1; off < 64; off <<= 1) {
        s_loss += __shfl_xor(s_loss, off, 64);
        s_cp   += __shfl_xor(s_cp, off, 64);
        s_cn   += __shfl_xor(s_cn, off, 64);
        s_pr   += __shfl_xor(s_pr, off, 64);
        s_nr   += __shfl_xor(s_nr, off, 64);
    }
    if (lane == 0) {
        redbuf[wv][0] = s_loss; redbuf[wv][1] = s_cp; redbuf[wv][2] = s_cn;
        redbuf[wv][3] = s_pr;   redbuf[wv][4] = s_nr;
    }
    __syncthreads();
    if (tid == 0) {
        float t0 = 0.f, t1 = 0.f, t2 = 0.f, t3 = 0.f, t4 = 0.f;
        for (int w = 0; w < 4; ++w) {
            t0 += redbuf[w][0]; t1 += redbuf[w][1]; t2 += redbuf[w][2];
            t3 += redbuf[w][3]; t4 += redbuf[w][4];
        }
        part[blk * 8 + 0] = t0; part[blk * 8 + 1] = t1; part[blk * 8 + 2] = t2;
        part[blk * 8 + 3] = t3; part[blk * 8 + 4] = t4;
    }
}

// ---------------- kernel 3: fold 2048 block partials ------------------------
__global__ void final_reduce(const float* __restrict__ part, float* __restrict__ out) {
    __shared__ float red[4][8];
    const int tid = threadIdx.x;
    const int lane = tid & 63, wv = tid >> 6;
    float a0 = 0.f, a1 = 0.f, a2 = 0.f, a3 = 0.f, a4 = 0.f;
    for (int b = tid; b < NBLKS; b += 256) {
        a0 += part[b * 8 + 0]; a1 += part[b * 8 + 1]; a2 += part[b * 8 + 2];
        a3 += part[b * 8 + 3]; a4 += part[b * 8 + 4];
    }
    #pragma unroll
    for (int off = 1; off < 64; off <<= 1) {
        a0 += __shfl_xor(a0, off, 64); a1 += __shfl_xor(a1, off, 64);
        a2 += __shfl_xor(a2, off, 64); a3 += __shfl_xor(a3, off, 64);
        a4 += __shfl_xor(a4, off, 64);
    }
    if (lane == 0) { red[wv][0] = a0; red[wv][1] = a1; red[wv][2] = a2; red[wv][3] = a3; red[wv][4] = a4; }
    __syncthreads();
    if (tid == 0) {
        float t0 = 0.f, t1 = 0.f, t2 = 0.f, t3 = 0.f, t4 = 0.f;
        for (int w = 0; w < 4; ++w) {
            t0 += red[w][0]; t1 += red[w][1]; t2 += red[w][2]; t3 += red[w][3]; t4 += red[w][4];
        }
        out[NROWS + 0] = -t0 / (float)NROWS;       // loss
        out[NROWS + 1] = t3 / t1;                  // recall_pos
        out[NROWS + 2] = t4 / t2;                  // recall_neg
        out[NROWS + 3] = (t3 + t4) / (t1 + t2);    // recall_all
    }
}

extern "C" void kernel_launch(void* const* d_in, const int* in_sizes, int n_in,
                              void* d_out, int out_size, void* d_ws, size_t ws_size,
                              hipStream_t stream) {
    const float* sbj   = (const float*)d_in[0];
    const float* obj   = (const float*)d_in[1];
    const float* rlts  = (const float*)d_in[2];
    const float* spa_w = (const float*)d_in[3];
    const float* spa_b = (const float*)d_in[4];
    const float* w1    = (const float*)d_in[5];
    const float* b1    = (const float*)d_in[6];
    const float* w2    = (const float*)d_in[7];
    const float* b2    = (const float*)d_in[8];
    float* out = (float*)d_out;

    unsigned short* wt = (unsigned short*)d_ws;
    float* part = (float*)((char*)d_ws + PART_OFF);

    prep_w1<<<(WT_ELEMS + 255) / 256, 256, 0, stream>>>(w1, wt);
    main_kernel<<<NBLKS, 256, 0, stream>>>(sbj, obj, rlts, spa_w, spa_b, b1, w2, b2, wt, out, part);
    final_reduce<<<1, 256, 0, stream>>>(part, out);
}

// Round 3
// 376.046 us; speedup vs baseline: 1.0673x; 1.0117x over previous
//
#include <hip/hip_runtime.h>

constexpr int NROWS  = 131072;
constexpr int LDIM   = 300;
constexpr int KDIM   = 600;
constexpr int NPAD   = 320;
constexpr int KGRP   = 76;               // 608 / 8
constexpr int MTILE  = 64;
constexpr int NBLKS  = NROWS / MTILE;    // 2048
constexpr int KSTEPS = 19;               // 608 / 32
constexpr int WT_ELEMS = KGRP * NPAD * 8;        // 194560 bf16
constexpr size_t PART_OFF = 393216;              // byte offset of partials in ws
constexpr int ASTRIDE = 40;              // shorts per row (80 B) — conflict-free

typedef __bf16 bf16x8 __attribute__((ext_vector_type(8)));
typedef float  f32x4  __attribute__((ext_vector_type(4)));

__device__ __forceinline__ unsigned short f2bf(float f) {
    unsigned u = __float_as_uint(f);
    u += 0x7fffu + ((u >> 16) & 1u);      // RNE; inputs are finite
    return (unsigned short)(u >> 16);
}

// ---------------- kernel 1: W1 -> bf16, fragment-ready layout [kg][n][j] ----
__global__ void prep_w1(const float* __restrict__ w1, unsigned short* __restrict__ wt) {
    int idx = blockIdx.x * 256 + threadIdx.x;
    if (idx >= WT_ELEMS) return;
    int j    = idx & 7;
    int rest = idx >> 3;
    int n    = rest % NPAD;
    int kg   = rest / NPAD;
    int k    = kg * 8 + j;
    float v = 0.f;
    if (k < KDIM && n < LDIM) v = w1[k * LDIM + n];
    wt[idx] = f2bf(v);
}

// ---------------- kernel 2: fused GEMM + epilogue ---------------------------
// The K-loop uses RAW s_barrier (no fence): __syncthreads() would emit
// s_waitcnt vmcnt(0) and drain the prefetch queue every iteration — that drain
// was the entire bottleneck of rounds 0-2. With raw barriers + reg-double-
// buffered B + depth-3 A prefetch, the compiler's automatic counted waitcnt
// keeps 7 vmem ops in flight across every barrier (T3/T4 discipline).
__launch_bounds__(256, 2)
__global__ void main_kernel(const float* __restrict__ sbj, const float* __restrict__ obj,
                            const float* __restrict__ rlts,
                            const float* __restrict__ spa_w, const float* __restrict__ spa_b,
                            const float* __restrict__ b1, const float* __restrict__ w2,
                            const float* __restrict__ b2,
                            const unsigned short* __restrict__ wt,
                            float* __restrict__ out_scores, float* __restrict__ part) {
    __shared__ __attribute__((aligned(16))) short A_lds[2][MTILE * ASTRIDE]; // 10240 B
    __shared__ float lanpart[4][MTILE];
    __shared__ float redbuf[4][8];

    const int tid  = threadIdx.x;
    const int lane = tid & 63;
    const int wv   = tid >> 6;     // 0..3 — each wave owns 80 cols
    const int l4   = lane & 15;    // MFMA row/col index
    const int q4   = lane >> 4;    // MFMA k-group (0..3)
    const int nbase = wv * 80;

    const int  blk  = blockIdx.x;
    const long row0 = (long)blk * MTILE;

    // A staging map: thread t loads rows (t>>3) and (t>>3)+32, k-quad t&7
    const int a_quad = tid & 7;
    const int a_row  = tid >> 3;   // 0..31

    f32x4 acc[4][5];
    #pragma unroll
    for (int rt = 0; rt < 4; ++rt)
        #pragma unroll
        for (int ct = 0; ct < 5; ++ct)
            acc[rt][ct] = (f32x4)(0.f);

    float4 pre[3][2];              // 3 rotating A slots, static-indexed (full unroll)
    bf16x8 bfr[2][5];              // double-buffered B fragments

    const unsigned short* wbase = wt + ((size_t)q4 * NPAD + nbase + l4) * 8;

    auto load_A = [&](int kt, int slot) {
        const int k0 = kt * 32 + a_quad * 4;   // mult of 4; 300 % 4 == 0 → no straddle
        #pragma unroll
        for (int i = 0; i < 2; ++i) {
            const long grow = row0 + a_row + i * 32;
            if (k0 < LDIM)       pre[slot][i] = *(const float4*)(sbj + grow * LDIM + k0);
            else if (k0 < KDIM)  pre[slot][i] = *(const float4*)(obj + grow * LDIM + (k0 - LDIM));
            else                 pre[slot][i] = make_float4(0.f, 0.f, 0.f, 0.f);
        }
    };
    auto load_B = [&](int kt, int rb) {
        #pragma unroll
        for (int ct = 0; ct < 5; ++ct)
            bfr[rb][ct] = *(const bf16x8*)(wbase + (size_t)kt * 4 * NPAD * 8 + ct * 16 * 8);
    };
    auto store_A = [&](int slot, int buf) {
        #pragma unroll
        for (int i = 0; i < 2; ++i) {
            const int row = a_row + i * 32;
            unsigned h0 = f2bf(fmaxf(pre[slot][i].x, 0.f));
            unsigned h1 = f2bf(fmaxf(pre[slot][i].y, 0.f));
            unsigned h2 = f2bf(fmaxf(pre[slot][i].z, 0.f));
            unsigned h3 = f2bf(fmaxf(pre[slot][i].w, 0.f));
            uint2 pk = make_uint2(h0 | (h1 << 16), h2 | (h3 << 16));
            *(uint2*)&A_lds[buf][row * ASTRIDE + a_quad * 4] = pk;
        }
    };

    // Prologue: B(0) first (needed soonest), then A pipeline 3 deep.
    load_B(0, 0);
    load_A(0, 0);
    load_A(1, 1);
    load_A(2, 2);
    store_A(0, 0);                 // compiler waits (counted) only up to A(0)
    asm volatile("s_waitcnt lgkmcnt(0)" ::: "memory");
    __builtin_amdgcn_s_barrier();  // raw: B(0) tail + A(1),A(2) stay in flight

    #pragma unroll
    for (int kt = 0; kt < KSTEPS; ++kt) {
        const int buf = kt & 1;

        // A fragments from LDS (conflict-free stride-40 layout)
        bf16x8 af[4];
        #pragma unroll
        for (int rt = 0; rt < 4; ++rt)
            af[rt] = *(const bf16x8*)&A_lds[buf][(rt * 16 + l4) * ASTRIDE + q4 * 8];

        // Prefetch next-iter B and A three ahead (stay in flight across barrier)
        if (kt + 1 < KSTEPS) load_B(kt + 1, (kt + 1) & 1);
        if (kt + 3 < KSTEPS) load_A(kt + 3, kt % 3);

        // MFMAs consume B(kt) loaded LAST iteration → compiler emits a counted
        // vmcnt (≈9) here, never 0: B(kt+1)/A(kt+3) remain outstanding.
        #pragma unroll
        for (int ct = 0; ct < 5; ++ct)
            #pragma unroll
            for (int rt = 0; rt < 4; ++rt)
                acc[rt][ct] = __builtin_amdgcn_mfma_f32_16x16x32_bf16(af[rt], bfr[buf][ct], acc[rt][ct], 0, 0, 0);

        // Commit A(kt+1) (loaded 2 iters ago — already drained by the counted
        // wait above), publish via lgkmcnt(0) + RAW barrier (no vmem drain).
        if (kt + 1 < KSTEPS) {
            store_A((kt + 1) % 3, buf ^ 1);
            asm volatile("s_waitcnt lgkmcnt(0)" ::: "memory");
            __builtin_amdgcn_s_barrier();
        }
    }

    // ---- epilogue: bias + relu + dot with w2 ----
    // C/D layout (m89): col = lane&15, row = (lane>>4)*4 + reg
    float part_r[4][4];
    #pragma unroll
    for (int rt = 0; rt < 4; ++rt)
        #pragma unroll
        for (int r = 0; r < 4; ++r) part_r[rt][r] = 0.f;

    #pragma unroll
    for (int ct = 0; ct < 5; ++ct) {
        const int n = nbase + ct * 16 + l4;
        if (n < LDIM) {
            const float b1n = b1[n];
            const float w2n = w2[n];
            #pragma unroll
            for (int rt = 0; rt < 4; ++rt)
                #pragma unroll
                for (int r = 0; r < 4; ++r) {
                    float h = fmaxf(acc[rt][ct][r] + b1n, 0.f);
                    part_r[rt][r] = fmaf(h, w2n, part_r[rt][r]);
                }
        }
    }
    // reduce over the 16 col-lanes (xor of lane bits 0..3)
    #pragma unroll
    for (int off = 1; off < 16; off <<= 1)
        #pragma unroll
        for (int rt = 0; rt < 4; ++rt)
            #pragma unroll
            for (int r = 0; r < 4; ++r)
                part_r[rt][r] += __shfl_xor(part_r[rt][r], off, 64);

    if (l4 == 0) {
        #pragma unroll
        for (int rt = 0; rt < 4; ++rt)
            #pragma unroll
            for (int r = 0; r < 4; ++r)
                lanpart[wv][rt * 16 + q4 * 4 + r] = part_r[rt][r];
    }
    __syncthreads();

    // ---- per-row: box features, sigmoid, loss terms ----
    float s_loss = 0.f, s_cp = 0.f, s_cn = 0.f, s_pr = 0.f, s_nr = 0.f;
    if (tid < MTILE) {
        const long g   = row0 + tid;
        const float lan = lanpart[0][tid] + lanpart[1][tid] + lanpart[2][tid] + lanpart[3][tid] + b2[0];
        const float* rr = rlts + g * 15;
        const float label = rr[4];
        const float sx1 = rr[5],  sy1 = rr[6],  sx2 = rr[7],  sy2 = rr[8];
        const float ox1 = rr[10], oy1 = rr[11], ox2 = rr[12], oy2 = rr[13];
        const float sw = sx2 - sx1, sh = sy2 - sy1, ow = ox2 - ox1, oh = oy2 - oy1;
        float bs = spa_w[0] * ((sx1 - ox1) / sw)
                 + spa_w[1] * ((sy1 - oy1) / sh)
                 + spa_w[2] * logf(sw / ow)
                 + spa_w[3] * logf(sh / oh)
                 + spa_w[4] * ((ox1 - sx1) / ow)
                 + spa_w[5] * ((oy1 - sy1) / oh)
                 + spa_w[6] * logf(ow / sw)
                 + spa_w[7] * logf(oh / sh)
                 + spa_b[0];
        const float z = lan + bs;
        const float s = 1.f / (1.f + expf(-z));
        out_scores[g] = s;
        const float ls = fmaxf(logf(fminf(fmaxf(s, 1e-12f), 1.f)), -100.f);
        const float l1 = fmaxf(logf(fminf(fmaxf(1.f - s, 1e-12f), 1.f)), -100.f);
        const bool ys = label > 0.f;
        s_loss = ys ? ls : l1;
        s_cp   = ys ? 1.f : 0.f;
        s_cn   = ys ? 0.f : 1.f;
        s_pr   = (!ys && s >= 0.5f) ? 1.f : 0.f;  // "N_pos_right" per reference
        s_nr   = (ys && s < 0.5f)  ? 1.f : 0.f;   // "N_neg_right" per reference
    }
    #pragma unroll
    for (int off = 1; off < 64; off <<= 1) {
        s_loss += __shfl_xor(s_loss, off, 64);
        s_cp   += __shfl_xor(s_cp, off, 64);
        s_cn   += __shfl_xor(s_cn, off, 64);
        s_pr   += __shfl_xor(s_pr, off, 64);
        s_nr   += __shfl_xor(s_nr, off, 64);
    }
    if (lane == 0) {
        redbuf[wv][0] = s_loss; redbuf[wv][1] = s_cp; redbuf[wv][2] = s_cn;
        redbuf[wv][3] = s_pr;   redbuf[wv][4] = s_nr;
    }
    __syncthreads();
    if (tid == 0) {
        float t0 = 0.f, t1 = 0.f, t2 = 0.f, t3 = 0.f, t4 = 0.f;
        for (int w = 0; w < 4; ++w) {
            t0 += redbuf[w][0]; t1 += redbuf[w][1]; t2 += redbuf[w][2];
            t3 += redbuf[w][3]; t4 += redbuf[w][4];
        }
        part[blk * 8 + 0] = t0; part[blk * 8 + 1] = t1; part[blk * 8 + 2] = t2;
        part[blk * 8 + 3] = t3; part[blk * 8 + 4] = t4;
    }
}

// ---------------- kernel 3: fold 2048 block partials ------------------------
__global__ void final_reduce(const float* __restrict__ part, float* __restrict__ out) {
    __shared__ float red[4][8];
    const int tid = threadIdx.x;
    const int lane = tid & 63, wv = tid >> 6;
    float a0 = 0.f, a1 = 0.f, a2 = 0.f, a3 = 0.f, a4 = 0.f;
    for (int b = tid; b < NBLKS; b += 256) {
        a0 += part[b * 8 + 0]; a1 += part[b * 8 + 1]; a2 += part[b * 8 + 2];
        a3 += part[b * 8 + 3]; a4 += part[b * 8 + 4];
    }
    #pragma unroll
    for (int off = 1; off < 64; off <<= 1) {
        a0 += __shfl_xor(a0, off, 64); a1 += __shfl_xor(a1, off, 64);
        a2 += __shfl_xor(a2, off, 64); a3 += __shfl_xor(a3, off, 64);
        a4 += __shfl_xor(a4, off, 64);
    }
    if (lane == 0) { red[wv][0] = a0; red[wv][1] = a1; red[wv][2] = a2; red[wv][3] = a3; red[wv][4] = a4; }
    __syncthreads();
    if (tid == 0) {
        float t0 = 0.f, t1 = 0.f, t2 = 0.f, t3 = 0.f, t4 = 0.f;
        for (int w = 0; w < 4; ++w) {
            t0 += red[w][0]; t1 += red[w][1]; t2 += red[w][2]; t3 += red[w][3]; t4 += red[w][4];
        }
        out[NROWS + 0] = -t0 / (float)NROWS;       // loss
        out[NROWS + 1] = t3 / t1;                  // recall_pos
        out[NROWS + 2] = t4 / t2;                  // recall_neg
        out[NROWS + 3] = (t3 + t4) / (t1 + t2);    // recall_all
    }
}

extern "C" void kernel_launch(void* const* d_in, const int* in_sizes, int n_in,
                              void* d_out, int out_size, void* d_ws, size_t ws_size,
                              hipStream_t stream) {
    const float* sbj   = (const float*)d_in[0];
    const float* obj   = (const float*)d_in[1];
    const float* rlts  = (const float*)d_in[2];
    const float* spa_w = (const float*)d_in[3];
    const float* spa_b = (const float*)d_in[4];
    const float* w1    = (const float*)d_in[5];
    const float* b1    = (const float*)d_in[6];
    const float* w2    = (const float*)d_in[7];
    const float* b2    = (const float*)d_in[8];
    float* out = (float*)d_out;

    unsigned short* wt = (unsigned short*)d_ws;
    float* part = (float*)((char*)d_ws + PART_OFF);

    prep_w1<<<(WT_ELEMS + 255) / 256, 256, 0, stream>>>(w1, wt);
    main_kernel<<<NBLKS, 256, 0, stream>>>(sbj, obj, rlts, spa_w, spa_b, b1, w2, b2, wt, out, part);
    final_reduce<<<1, 256, 0, stream>>>(part, out);
}